// Round 1
// baseline (57.935 us; speedup 1.0000x reference)
//
#include <hip/hip_runtime.h>
#include <math.h>

namespace {

constexpr int D  = 256;
constexpr int H  = 8;
constexpr int PAD = 260;   // floats; 260%32=4 -> conflict-free bank quads; %4==0 -> float4 aligned

// ---------------- Kernel 1: qW[bn,h,e] = sum_d q[bn,d] * W[h,d,e] ----------------
// grid (BN/16, H), block 256. Thread owns 4 rows x 4 e. q staged transposed in LDS
// so the per-d read is one broadcast ds_read_b128; W read coalesced float4.
__global__ __launch_bounds__(256) void qw_kernel(
    const float* __restrict__ q, const float* __restrict__ W,
    float* __restrict__ qW) {
  __shared__ float qT[256][20];   // [d][row], pad 20 (%4==0 for float4 align)
  const int tid = threadIdx.x;
  const int bn0 = blockIdx.x * 16;
  const int h   = blockIdx.y;
  for (int i = 0; i < 16; ++i)
    qT[tid][i] = q[(size_t)(bn0 + i) * D + tid];
  __syncthreads();

  const int r0 = (tid >> 6) << 2;   // 0,4,8,12
  const int e0 = (tid & 63) << 2;   // 0..252
  float acc[4][4];
  #pragma unroll
  for (int r = 0; r < 4; ++r)
    #pragma unroll
    for (int e = 0; e < 4; ++e) acc[r][e] = 0.f;

  const float4* W4 = reinterpret_cast<const float4*>(W + (size_t)h * D * D);
  const int ecol = e0 >> 2;
  for (int d = 0; d < D; ++d) {
    float4 qv = *reinterpret_cast<const float4*>(&qT[d][r0]);  // broadcast (all lanes same addr)
    float4 wv = W4[d * 64 + ecol];                              // coalesced
    const float qa[4] = {qv.x, qv.y, qv.z, qv.w};
    const float wa[4] = {wv.x, wv.y, wv.z, wv.w};
    #pragma unroll
    for (int r = 0; r < 4; ++r)
      #pragma unroll
      for (int e = 0; e < 4; ++e)
        acc[r][e] += qa[r] * wa[e];
  }
  #pragma unroll
  for (int r = 0; r < 4; ++r) {
    float4 o = make_float4(acc[r][0], acc[r][1], acc[r][2], acc[r][3]);
    *reinterpret_cast<float4*>(&qW[(size_t)(bn0 + r0 + r) * (H * D) + h * D + e0]) = o;
  }
}

// ---------------- Kernel 2: scores + reshape-softmax + PV ----------------
// One block per (b,n). scores flat j = k*8+h; softmax over consecutive 64-chunks
// (this IS the reshape(B,N,H,K) semantics); out[d] = sum_k (sum_h attn[h*64+k]) v[k,d].
__global__ __launch_bounds__(256) void attn_kernel(
    const float* __restrict__ qW, const float* __restrict__ kin,
    const float* __restrict__ vin, const float* __restrict__ bin,
    float* __restrict__ out, float* __restrict__ attn_out) {
  __shared__ float k_lds[32][PAD];
  __shared__ float qW_lds[H][PAD];
  __shared__ float s_lds[512];
  __shared__ float wsum[64];
  const int tid = threadIdx.x;
  const int bn  = blockIdx.x;

  // stage qW (8 rows x 256) as float4
  const float4* qw4 = reinterpret_cast<const float4*>(qW) + (size_t)bn * 512;
  for (int i = tid; i < 512; i += 256) {
    float4 vql = qw4[i];
    *reinterpret_cast<float4*>(&qW_lds[i >> 6][(i & 63) << 2]) = vql;
  }

  const float bias = bin[tid & 7];
  const float4* kv4 = reinterpret_cast<const float4*>(kin) + (size_t)bn * 4096;
  const int h = tid & 7, krow = tid >> 3;   // krow 0..31

  #pragma unroll
  for (int half = 0; half < 2; ++half) {
    __syncthreads();  // covers qW/k_lds writes (and k_lds reuse on half=1)
    for (int i = tid; i < 2048; i += 256) {
      int r = i >> 6, c4 = i & 63;
      *reinterpret_cast<float4*>(&k_lds[r][c4 << 2]) = kv4[(half * 32 + r) * 64 + c4];
    }
    __syncthreads();
    float acc = bias;
    for (int e = 0; e < D; e += 4) {
      float4 a  = *reinterpret_cast<const float4*>(&qW_lds[h][e]);
      float4 kk = *reinterpret_cast<const float4*>(&k_lds[krow][e]);
      acc += a.x * kk.x + a.y * kk.y + a.z * kk.z + a.w * kk.w;
    }
    s_lds[half * 256 + tid] = acc;   // == (half*32+krow)*8 + h
  }
  __syncthreads();

  // softmax over each consecutive 64-chunk; wave w handles chunks 2w, 2w+1
  const int wv = tid >> 6, ln = tid & 63;
  #pragma unroll
  for (int i = 0; i < 2; ++i) {
    int c = wv * 2 + i;
    float x = s_lds[c * 64 + ln];
    float m = x;
    #pragma unroll
    for (int off = 32; off; off >>= 1) m = fmaxf(m, __shfl_xor(m, off, 64));
    float e = expf(x - m);
    float s = e;
    #pragma unroll
    for (int off = 32; off; off >>= 1) s += __shfl_xor(s, off, 64);
    float a = e / s;
    s_lds[c * 64 + ln] = a;
    attn_out[(size_t)bn * 512 + c * 64 + ln] = a;
  }
  __syncthreads();

  // v-row weights: wsum[k] = sum_h2 attn_flat[h2*64 + k]
  if (tid < 64) {
    float ws = 0.f;
    #pragma unroll
    for (int h2 = 0; h2 < 8; ++h2) ws += s_lds[h2 * 64 + tid];
    wsum[tid] = ws;
  }
  __syncthreads();

  float acc = 0.f;
  const float* vrow = vin + (size_t)bn * (64 * D) + tid;
  for (int kk2 = 0; kk2 < 64; ++kk2) acc += wsum[kk2] * vrow[kk2 * D];
  out[(size_t)bn * D + tid] = acc;
}

}  // namespace

extern "C" void kernel_launch(void* const* d_in, const int* in_sizes, int n_in,
                              void* d_out, int out_size, void* d_ws, size_t ws_size,
                              hipStream_t stream) {
  const float* q = (const float*)d_in[0];   // (8,128,1,256)
  const float* k = (const float*)d_in[1];   // (8,128,64,256)
  const float* v = (const float*)d_in[2];   // (8,128,64,256)
  const float* W = (const float*)d_in[3];   // (8,256,256)
  const float* b = (const float*)d_in[4];   // (8,)

  float* out  = (float*)d_out;              // output: 8*128*256 = 262144 f32
  float* attn = out + 262144;               // attn:   8*128*8*64 = 524288 f32
  float* qWbuf = (float*)d_ws;              // 1024*2048 f32 = 8 MiB scratch

  hipLaunchKernelGGL(qw_kernel, dim3(64, 8), dim3(256), 0, stream, q, W, qWbuf);
  hipLaunchKernelGGL(attn_kernel, dim3(1024), dim3(256), 0, stream, qWbuf, k, v, b, out, attn);
}

// Round 2
// 55.884 us; speedup vs baseline: 1.0367x; 1.0367x over previous
//
#include <hip/hip_runtime.h>
#include <math.h>

namespace {

constexpr int D  = 256;
constexpr int H  = 8;

// ---------------- Kernel 1: qW[bn,h,e] = sum_d q[bn,d] * W[h,d,e] ----------------
// grid (BN/16, H), block 256. Thread owns 4 rows x 4 e. q staged transposed in LDS
// so the per-d read is one broadcast ds_read_b128; W read coalesced float4.
__global__ __launch_bounds__(256) void qw_kernel(
    const float* __restrict__ q, const float* __restrict__ W,
    float* __restrict__ qW) {
  __shared__ float qT[256][20];   // [d][row], pad 20 (%4==0 for float4 align)
  const int tid = threadIdx.x;
  const int bn0 = blockIdx.x * 16;
  const int h   = blockIdx.y;
  for (int i = 0; i < 16; ++i)
    qT[tid][i] = q[(size_t)(bn0 + i) * D + tid];
  __syncthreads();

  const int r0 = (tid >> 6) << 2;   // 0,4,8,12
  const int e0 = (tid & 63) << 2;   // 0..252
  float acc[4][4];
  #pragma unroll
  for (int r = 0; r < 4; ++r)
    #pragma unroll
    for (int e = 0; e < 4; ++e) acc[r][e] = 0.f;

  const float4* W4 = reinterpret_cast<const float4*>(W + (size_t)h * D * D);
  const int ecol = e0 >> 2;
  for (int d = 0; d < D; ++d) {
    float4 qv = *reinterpret_cast<const float4*>(&qT[d][r0]);  // broadcast
    float4 wv = W4[d * 64 + ecol];                              // coalesced
    const float qa[4] = {qv.x, qv.y, qv.z, qv.w};
    const float wa[4] = {wv.x, wv.y, wv.z, wv.w};
    #pragma unroll
    for (int r = 0; r < 4; ++r)
      #pragma unroll
      for (int e = 0; e < 4; ++e)
        acc[r][e] += qa[r] * wa[e];
  }
  #pragma unroll
  for (int r = 0; r < 4; ++r) {
    float4 o = make_float4(acc[r][0], acc[r][1], acc[r][2], acc[r][3]);
    *reinterpret_cast<float4*>(&qW[(size_t)(bn0 + r0 + r) * (H * D) + h * D + e0]) = o;
  }
}

// ---------------- Kernel 2: scores + reshape-softmax + PV (fused, low-LDS) ----------------
// One block per (b,n), 256 threads = 4 waves.
// scores flat j = k*8+h; softmax over consecutive 64-chunks (== reshape(B,N,H,K));
// out[d] = sum_kk wsum[kk] * v[kk,d] with wsum[kk] = sum_c attn_flat[c*64+kk].
__global__ __launch_bounds__(256) void attn_kernel(
    const float* __restrict__ qW, const float* __restrict__ kin,
    const float* __restrict__ vin, const float* __restrict__ bin,
    float* __restrict__ out, float* __restrict__ attn_out) {
  __shared__ float qW_lds[H][260];
  __shared__ float s_lds[512];
  __shared__ float wpart[4][64];
  __shared__ float s_red[4][260];
  const int tid = threadIdx.x;
  const int bn  = blockIdx.x;
  const int wid = tid >> 6;
  const int ln  = tid & 63;

  // stage qW (8 rows x 256) as float4, coalesced
  const float4* qw4 = reinterpret_cast<const float4*>(qW) + (size_t)bn * 512;
  {
    float4 v0 = qw4[tid];
    float4 v1 = qw4[tid + 256];
    *reinterpret_cast<float4*>(&qW_lds[tid >> 6][(tid & 63) << 2]) = v0;
    *reinterpret_cast<float4*>(&qW_lds[(tid + 256) >> 6][(tid & 63) << 2]) = v1;
  }
  __syncthreads();

  // ---- Phase A: scores. Thread owns (krow = tid>>2, h = tid&3 and (tid&3)+4).
  // 4 lanes share a k row -> same address per instr -> HW broadcast, k read once.
  {
    const int krow = tid >> 2;
    const int hp   = tid & 3;
    const float4* k4  = reinterpret_cast<const float4*>(kin) + (size_t)bn * 4096 + krow * 64;
    const float4* a04 = reinterpret_cast<const float4*>(&qW_lds[hp][0]);
    const float4* a14 = reinterpret_cast<const float4*>(&qW_lds[hp + 4][0]);
    float acc0 = bin[hp], acc1 = bin[hp + 4];
    #pragma unroll 8
    for (int e4 = 0; e4 < 64; ++e4) {
      float4 kv = k4[e4];
      float4 a0 = a04[e4];
      float4 a1 = a14[e4];
      acc0 += a0.x * kv.x + a0.y * kv.y + a0.z * kv.z + a0.w * kv.w;
      acc1 += a1.x * kv.x + a1.y * kv.y + a1.z * kv.z + a1.w * kv.w;
    }
    s_lds[krow * 8 + hp]     = acc0;
    s_lds[krow * 8 + hp + 4] = acc1;
  }
  __syncthreads();

  // ---- Phase B: softmax over chunks 2*wid, 2*wid+1; write attn + wave partial of wsum.
  {
    float wp = 0.f;
    #pragma unroll
    for (int i = 0; i < 2; ++i) {
      const int c = wid * 2 + i;
      float x = s_lds[c * 64 + ln];
      float m = x;
      #pragma unroll
      for (int off = 32; off; off >>= 1) m = fmaxf(m, __shfl_xor(m, off, 64));
      float e = expf(x - m);
      float s = e;
      #pragma unroll
      for (int off = 32; off; off >>= 1) s += __shfl_xor(s, off, 64);
      float a = e / s;
      attn_out[(size_t)bn * 512 + c * 64 + ln] = a;
      wp += a;
    }
    wpart[wid][ln] = wp;
  }
  __syncthreads();

  // ---- Phase D: PV. Wave wid owns v rows [wid*16, wid*16+16); lane ln owns d4 = 4*ln.
  {
    const float4* v4p = reinterpret_cast<const float4*>(vin) + (size_t)bn * 4096;
    float4 acc = make_float4(0.f, 0.f, 0.f, 0.f);
    #pragma unroll 4
    for (int i = 0; i < 16; ++i) {
      const int kr = wid * 16 + i;
      float w = wpart[0][kr] + wpart[1][kr] + wpart[2][kr] + wpart[3][kr];
      float4 vv = v4p[kr * 64 + ln];
      acc.x += w * vv.x; acc.y += w * vv.y; acc.z += w * vv.z; acc.w += w * vv.w;
    }
    *reinterpret_cast<float4*>(&s_red[wid][ln << 2]) = acc;
  }
  __syncthreads();

  {
    float val = s_red[0][tid] + s_red[1][tid] + s_red[2][tid] + s_red[3][tid];
    out[(size_t)bn * D + tid] = val;
  }
}

}  // namespace

extern "C" void kernel_launch(void* const* d_in, const int* in_sizes, int n_in,
                              void* d_out, int out_size, void* d_ws, size_t ws_size,
                              hipStream_t stream) {
  const float* q = (const float*)d_in[0];   // (8,128,1,256)
  const float* k = (const float*)d_in[1];   // (8,128,64,256)
  const float* v = (const float*)d_in[2];   // (8,128,64,256)
  const float* W = (const float*)d_in[3];   // (8,256,256)
  const float* b = (const float*)d_in[4];   // (8,)

  float* out  = (float*)d_out;              // output: 8*128*256 = 262144 f32
  float* attn = out + 262144;               // attn:   8*128*8*64 = 524288 f32
  float* qWbuf = (float*)d_ws;              // 1024*2048 f32 = 8 MiB scratch

  hipLaunchKernelGGL(qw_kernel, dim3(64, 8), dim3(256), 0, stream, q, W, qWbuf);
  hipLaunchKernelGGL(attn_kernel, dim3(1024), dim3(256), 0, stream, qWbuf, k, v, b, out, attn);
}

// Round 3
// 49.014 us; speedup vs baseline: 1.1820x; 1.1402x over previous
//
#include <hip/hip_runtime.h>
#include <math.h>

namespace {

constexpr int D  = 256;
constexpr int H  = 8;

// ---------------- Kernel 1: qW[bn,h,e] = sum_d q[bn,d] * W[h,d,e] ----------------
// (unchanged from round 2 — isolating the attn fix this round)
__global__ __launch_bounds__(256) void qw_kernel(
    const float* __restrict__ q, const float* __restrict__ W,
    float* __restrict__ qW) {
  __shared__ float qT[256][20];
  const int tid = threadIdx.x;
  const int bn0 = blockIdx.x * 16;
  const int h   = blockIdx.y;
  for (int i = 0; i < 16; ++i)
    qT[tid][i] = q[(size_t)(bn0 + i) * D + tid];
  __syncthreads();

  const int r0 = (tid >> 6) << 2;
  const int e0 = (tid & 63) << 2;
  float acc[4][4];
  #pragma unroll
  for (int r = 0; r < 4; ++r)
    #pragma unroll
    for (int e = 0; e < 4; ++e) acc[r][e] = 0.f;

  const float4* W4 = reinterpret_cast<const float4*>(W + (size_t)h * D * D);
  const int ecol = e0 >> 2;
  for (int d = 0; d < D; ++d) {
    float4 qv = *reinterpret_cast<const float4*>(&qT[d][r0]);
    float4 wv = W4[d * 64 + ecol];
    const float qa[4] = {qv.x, qv.y, qv.z, qv.w};
    const float wa[4] = {wv.x, wv.y, wv.z, wv.w};
    #pragma unroll
    for (int r = 0; r < 4; ++r)
      #pragma unroll
      for (int e = 0; e < 4; ++e)
        acc[r][e] += qa[r] * wa[e];
  }
  #pragma unroll
  for (int r = 0; r < 4; ++r) {
    float4 o = make_float4(acc[r][0], acc[r][1], acc[r][2], acc[r][3]);
    *reinterpret_cast<float4*>(&qW[(size_t)(bn0 + r0 + r) * (H * D) + h * D + e0]) = o;
  }
}

// ---------------- Kernel 2: scores + reshape-softmax + PV ----------------
// One block per (b,n), 256 threads = 4 waves. Explicit 8-deep load batching
// (MLP fix): k loaded in float4 kb[8] batches; v rows prefetched into regs
// (half at kernel start, half before softmax) so PV has no latency chain.
__global__ __launch_bounds__(256, 4) void attn_kernel(
    const float* __restrict__ qW, const float* __restrict__ kin,
    const float* __restrict__ vin, const float* __restrict__ bin,
    float* __restrict__ out, float* __restrict__ attn_out) {
  __shared__ float qW_lds[H][260];
  __shared__ float s_lds[512];
  __shared__ float wpart[4][64];
  __shared__ float s_red[4][260];
  const int tid = threadIdx.x;
  const int bn  = blockIdx.x;
  const int wid = tid >> 6;
  const int ln  = tid & 63;

  // ---- Prefetch PV first-half v rows (wid*16 + 0..7), col4 = ln. Independent
  // of everything; latency hides under qW stage + phase A.
  const float4* v4p = reinterpret_cast<const float4*>(vin) + (size_t)bn * 4096;
  float4 vb0[8];
  #pragma unroll
  for (int j = 0; j < 8; ++j) vb0[j] = v4p[(wid * 16 + j) * 64 + ln];

  // ---- Stage qW (8 rows x 256) as float4, coalesced.
  const float4* qw4 = reinterpret_cast<const float4*>(qW) + (size_t)bn * 512;
  {
    float4 q0 = qw4[tid];
    float4 q1 = qw4[tid + 256];
    *reinterpret_cast<float4*>(&qW_lds[tid >> 6][(tid & 63) << 2]) = q0;
    *reinterpret_cast<float4*>(&qW_lds[(tid + 256) >> 6][(tid & 63) << 2]) = q1;
  }
  __syncthreads();

  // ---- Phase A: scores. Thread owns (krow = tid>>2, h = tid&3 and (tid&3)+4).
  // 8-deep explicit batches keep 8 loads in flight per wave.
  {
    const int krow = tid >> 2;
    const int hp   = tid & 3;
    const float4* k4  = reinterpret_cast<const float4*>(kin) + (size_t)bn * 4096 + krow * 64;
    const float4* a04 = reinterpret_cast<const float4*>(&qW_lds[hp][0]);
    const float4* a14 = reinterpret_cast<const float4*>(&qW_lds[hp + 4][0]);
    float acc0 = bin[hp], acc1 = bin[hp + 4];
    for (int blk = 0; blk < 8; ++blk) {
      float4 kb[8];
      #pragma unroll
      for (int j = 0; j < 8; ++j) kb[j] = k4[blk * 8 + j];
      #pragma unroll
      for (int j = 0; j < 8; ++j) {
        float4 a0 = a04[blk * 8 + j];
        float4 a1 = a14[blk * 8 + j];
        acc0 += a0.x * kb[j].x + a0.y * kb[j].y + a0.z * kb[j].z + a0.w * kb[j].w;
        acc1 += a1.x * kb[j].x + a1.y * kb[j].y + a1.z * kb[j].z + a1.w * kb[j].w;
      }
    }
    s_lds[krow * 8 + hp]     = acc0;
    s_lds[krow * 8 + hp + 4] = acc1;
  }
  __syncthreads();

  // ---- Prefetch PV second-half v rows (wid*16 + 8..15); hides under softmax.
  float4 vb1[8];
  #pragma unroll
  for (int j = 0; j < 8; ++j) vb1[j] = v4p[(wid * 16 + 8 + j) * 64 + ln];

  // ---- Phase B: softmax over chunks 2*wid, 2*wid+1 (reshape semantics:
  // flat j = k*8+h, chunks are consecutive 64-runs).
  {
    float wp = 0.f;
    #pragma unroll
    for (int i = 0; i < 2; ++i) {
      const int c = wid * 2 + i;
      float x = s_lds[c * 64 + ln];
      float m = x;
      #pragma unroll
      for (int off = 32; off; off >>= 1) m = fmaxf(m, __shfl_xor(m, off, 64));
      float e = expf(x - m);
      float s = e;
      #pragma unroll
      for (int off = 32; off; off >>= 1) s += __shfl_xor(s, off, 64);
      float a = e / s;
      attn_out[(size_t)bn * 512 + c * 64 + ln] = a;
      wp += a;
    }
    wpart[wid][ln] = wp;
  }
  __syncthreads();

  // ---- PV from prefetched registers; wsum via 4 broadcast LDS reads.
  {
    float4 acc = make_float4(0.f, 0.f, 0.f, 0.f);
    #pragma unroll
    for (int j = 0; j < 8; ++j) {
      const int kr = wid * 16 + j;
      float w = wpart[0][kr] + wpart[1][kr] + wpart[2][kr] + wpart[3][kr];
      acc.x += w * vb0[j].x; acc.y += w * vb0[j].y;
      acc.z += w * vb0[j].z; acc.w += w * vb0[j].w;
    }
    #pragma unroll
    for (int j = 0; j < 8; ++j) {
      const int kr = wid * 16 + 8 + j;
      float w = wpart[0][kr] + wpart[1][kr] + wpart[2][kr] + wpart[3][kr];
      acc.x += w * vb1[j].x; acc.y += w * vb1[j].y;
      acc.z += w * vb1[j].z; acc.w += w * vb1[j].w;
    }
    *reinterpret_cast<float4*>(&s_red[wid][ln << 2]) = acc;
  }
  __syncthreads();

  out[(size_t)bn * D + tid] =
      s_red[0][tid] + s_red[1][tid] + s_red[2][tid] + s_red[3][tid];
}

}  // namespace

extern "C" void kernel_launch(void* const* d_in, const int* in_sizes, int n_in,
                              void* d_out, int out_size, void* d_ws, size_t ws_size,
                              hipStream_t stream) {
  const float* q = (const float*)d_in[0];   // (8,128,1,256)
  const float* k = (const float*)d_in[1];   // (8,128,64,256)
  const float* v = (const float*)d_in[2];   // (8,128,64,256)
  const float* W = (const float*)d_in[3];   // (8,256,256)
  const float* b = (const float*)d_in[4];   // (8,)

  float* out  = (float*)d_out;              // output: 262144 f32
  float* attn = out + 262144;               // attn:   524288 f32
  float* qWbuf = (float*)d_ws;              // 1024*2048 f32 = 8 MiB scratch

  hipLaunchKernelGGL(qw_kernel, dim3(64, 8), dim3(256), 0, stream, q, W, qWbuf);
  hipLaunchKernelGGL(attn_kernel, dim3(1024), dim3(256), 0, stream, qWbuf, k, v, b, out, attn);
}